// Round 5
// baseline (16168.256 us; speedup 1.0000x reference)
//
#include <hip/hip_runtime.h>
#include <hip/hip_cooperative_groups.h>
#include <hip/hip_bf16.h>
#include <math.h>

#define BB 64
#define SS 64
#define DA 512
#define DM 2048
#define MM 25
#define NH 8
#define HD 64
#define NS 512
#define NOUT 1000
#define TT 50
#define HN 32
#define KTOT 2560
#define NOUT2 4096
#define KCH 640
#define NPAD 1024
#define SB2 ((size_t)BB*NS)

typedef __attribute__((ext_vector_type(8))) short bf16x8_t;
typedef __attribute__((ext_vector_type(8))) unsigned short u16x8_t;
typedef __attribute__((ext_vector_type(4))) float f32x4_t;

__device__ inline float bfs2f(unsigned short u){
    unsigned int x = ((unsigned int)u) << 16;
    return __uint_as_float(x);
}
__device__ inline unsigned short f2bfu(float v){
    __hip_bfloat16 h = __float2bfloat16(v);
    return *reinterpret_cast<unsigned short*>(&h);
}
__device__ inline float gelu_tanh(float x){
    float x3 = x*x*x;
    float u = 0.7978845608028654f*(x + 0.044715f*x3);
    float eu = __expf(2.f*u);
    float th = 1.f - 2.f/(eu + 1.f);
    return 0.5f*x*(1.0f + th);
}

// ---------------- workspace layout (float units) ----------------
static const size_t OFF_K     = 0;                                   // bf16 [B*S][DA]
static const size_t OFF_V     = OFF_K    + (size_t)BB*SS*DA/2;
static const size_t OFF_WCT   = OFF_V    + (size_t)BB*SS*DA/2;       // bf16 [4096][2560]
static const size_t OFF_WC1T  = OFF_WCT  + (size_t)NOUT2*KTOT/2;     // bf16 [512][512]
static const size_t OFF_WOUTT = OFF_WC1T + (size_t)DA*NS/2;          // bf16 [1024][512]
static const size_t OFF_WFK   = OFF_WOUTT+ (size_t)NPAD*NS/2;
static const size_t OFF_WFV   = OFF_WFK  + (size_t)DA*DA;
static const size_t OFF_BFK   = OFF_WFV  + (size_t)DA*DA;
static const size_t OFF_BFV   = OFF_BFK  + DA;
static const size_t OFF_BC1   = OFF_BFV  + DA;
static const size_t OFF_BC2   = OFF_BC1  + DA;
static const size_t OFF_BOUTP = OFF_BC2  + 2*DM;
static const size_t OFF_AA    = OFF_BOUTP+ NPAD;
static const size_t OFF_BA    = OFF_AA   + 2*SB2;
static const size_t OFF_AO    = OFF_BA   + 2*SB2;
static const size_t OFF_BO    = OFF_AO   + 2*SB2;
static const size_t OFF_SYA   = OFF_BO   + 2*SB2;                    // bf16 [64][512]
static const size_t OFF_ATTB  = OFF_SYA  + (size_t)BB*NS/2;          // bf16 [64][512]
static const size_t OFF_ACTB  = OFF_ATTB + (size_t)BB*DA/2;          // bf16 [64][2048]
static const size_t OFF_ACTF  = OFF_ACTB + (size_t)BB*DM/2;          // fp32 [64][2048]
static const size_t OFF_HPART = OFF_ACTF + (size_t)BB*DM;            // fp32 [4][64][4096]
static const size_t OFF_TRACE = OFF_HPART+ (size_t)4*BB*2*DM;        // fp32 [25][2048][64]
static const size_t OFF_PREDA = OFF_TRACE+ (size_t)MM*DM*BB;         // bf16 [50][64][1024]
static const size_t OFF_END   = OFF_PREDA+ (size_t)TT*BB*NPAD/2;

// ---------------- setup kernels (pre-loop, normal launches) ----------------
__global__ void sgemm64(const float* __restrict__ A, int lda,
                        const float* __restrict__ Bm, int ldb,
                        const float* __restrict__ bias,
                        float* __restrict__ C, int ldc, int Kdim)
{
    __shared__ float la[16][65];
    __shared__ float lb[16][64];
    int cg = blockIdx.x, rg = blockIdx.y, tid = threadIdx.x;
    int tx = tid & 15, ty = tid >> 4;
    const float* Ab = A + (size_t)rg*64*lda;
    const float* Bb = Bm + (size_t)cg*64;
    float acc[4][4] = {};
    for (int k0 = 0; k0 < Kdim; k0 += 16){
        for (int i = tid; i < 1024; i += 256){
            int r = i >> 4, kk = i & 15;
            la[kk][r] = Ab[(size_t)r*lda + k0 + kk];
        }
        for (int i = tid; i < 1024; i += 256){
            int kk = i >> 6, c = i & 63;
            lb[kk][c] = Bb[(size_t)(k0+kk)*ldb + c];
        }
        __syncthreads();
        #pragma unroll
        for (int kk = 0; kk < 16; ++kk){
            float av[4], bv[4];
            #pragma unroll
            for (int i = 0; i < 4; ++i) av[i] = la[kk][ty*4+i];
            #pragma unroll
            for (int j = 0; j < 4; ++j) bv[j] = lb[kk][tx*4+j];
            #pragma unroll
            for (int i = 0; i < 4; ++i)
                #pragma unroll
                for (int j = 0; j < 4; ++j) acc[i][j] += av[i]*bv[j];
        }
        __syncthreads();
    }
    for (int i = 0; i < 4; ++i){
        int row = rg*64 + ty*4 + i;
        for (int j = 0; j < 4; ++j){
            int col = cg*64 + tx*4 + j;
            float v = acc[i][j];
            if (bias) v += bias[col];
            C[(size_t)row*ldc + col] = v;
        }
    }
}

__global__ void sgemm64_bf16out(const float* __restrict__ A, int lda,
                                const float* __restrict__ Bm, int ldb,
                                const float* __restrict__ bias,
                                __hip_bfloat16* __restrict__ C, int ldc, int Kdim)
{
    __shared__ float la[16][65];
    __shared__ float lb[16][64];
    int cg = blockIdx.x, rg = blockIdx.y, tid = threadIdx.x;
    int tx = tid & 15, ty = tid >> 4;
    const float* Ab = A + (size_t)rg*64*lda;
    const float* Bb = Bm + (size_t)cg*64;
    float acc[4][4] = {};
    for (int k0 = 0; k0 < Kdim; k0 += 16){
        for (int i = tid; i < 1024; i += 256){
            int r = i >> 4, kk = i & 15;
            la[kk][r] = Ab[(size_t)r*lda + k0 + kk];
        }
        for (int i = tid; i < 1024; i += 256){
            int kk = i >> 6, c = i & 63;
            lb[kk][c] = Bb[(size_t)(k0+kk)*ldb + c];
        }
        __syncthreads();
        #pragma unroll
        for (int kk = 0; kk < 16; ++kk){
            float av[4], bv[4];
            #pragma unroll
            for (int i = 0; i < 4; ++i) av[i] = la[kk][ty*4+i];
            #pragma unroll
            for (int j = 0; j < 4; ++j) bv[j] = lb[kk][tx*4+j];
            #pragma unroll
            for (int i = 0; i < 4; ++i)
                #pragma unroll
                for (int j = 0; j < 4; ++j) acc[i][j] += av[i]*bv[j];
        }
        __syncthreads();
    }
    for (int i = 0; i < 4; ++i){
        int row = rg*64 + ty*4 + i;
        for (int j = 0; j < 4; ++j){
            int col = cg*64 + tx*4 + j;
            float v = acc[i][j];
            if (bias) v += bias[col];
            C[(size_t)row*ldc + col] = __float2bfloat16(v);
        }
    }
}

// Ct[n*ldct + k] = bf16( (A@B)[k][n] );  A is 512x512 (lda 512), B is 512 x N (ldb)
__global__ void gemm_t_bf16(const float* __restrict__ A, const float* __restrict__ Bm,
                            int ldb, unsigned short* __restrict__ Ct, int ldct)
{
    __shared__ float la[16][65];
    __shared__ float lb[16][64];
    int cg = blockIdx.x, rg = blockIdx.y, tid = threadIdx.x;
    int tx = tid & 15, ty = tid >> 4;
    const float* Ab = A + (size_t)rg*64*512;
    const float* Bb = Bm + (size_t)cg*64;
    float acc[4][4] = {};
    for (int k0 = 0; k0 < 512; k0 += 16){
        for (int i = tid; i < 1024; i += 256){
            int r = i >> 4, kk = i & 15;
            la[kk][r] = Ab[(size_t)r*512 + k0 + kk];
        }
        for (int i = tid; i < 1024; i += 256){
            int kk = i >> 6, c = i & 63;
            lb[kk][c] = Bb[(size_t)(k0+kk)*ldb + c];
        }
        __syncthreads();
        #pragma unroll
        for (int kk = 0; kk < 16; ++kk){
            float av[4], bv[4];
            #pragma unroll
            for (int i = 0; i < 4; ++i) av[i] = la[kk][ty*4+i];
            #pragma unroll
            for (int j = 0; j < 4; ++j) bv[j] = lb[kk][tx*4+j];
            #pragma unroll
            for (int i = 0; i < 4; ++i)
                #pragma unroll
                for (int j = 0; j < 4; ++j) acc[i][j] += av[i]*bv[j];
        }
        __syncthreads();
    }
    for (int i = 0; i < 4; ++i){
        int krow = rg*64 + ty*4 + i;
        for (int j = 0; j < 4; ++j){
            int ncol = cg*64 + tx*4 + j;
            Ct[(size_t)ncol*ldct + krow] = f2bfu(acc[i][j]);
        }
    }
}

// Ws1 rows 512..2559 -> WcT[n][512+r]
__global__ void tcvt_ws1(const float* __restrict__ Ws1, unsigned short* __restrict__ WcT)
{
    __shared__ float tile[32][33];
    int bx = blockIdx.x, by = blockIdx.y;
    int tx = threadIdx.x & 31, ty = threadIdx.x >> 5;
    for (int i = 0; i < 4; ++i){
        int r = by*32 + ty + i*8;
        tile[ty + i*8][tx] = Ws1[(size_t)(512 + r)*NOUT2 + bx*32 + tx];
    }
    __syncthreads();
    for (int i = 0; i < 4; ++i){
        int n = bx*32 + ty + i*8;
        int r = by*32 + tx;
        WcT[(size_t)n*KTOT + 512 + r] = f2bfu(tile[tx][ty + i*8]);
    }
}

// WoutT[n][k] = bf16(Wout[k][n]) (n<1000) else 0; boutp[n] = bout or 0
__global__ void tcvt_wout(const float* __restrict__ Wout, const float* __restrict__ bout,
                          unsigned short* __restrict__ WoutT, float* __restrict__ boutp)
{
    int n = blockIdx.x;
    int tid = threadIdx.x;
    for (int k = tid; k < NS; k += 256)
        WoutT[(size_t)n*NS + k] = (n < NOUT) ? f2bfu(Wout[(size_t)k*NOUT + n]) : (unsigned short)0;
    if (tid == 0) boutp[n] = (n < NOUT) ? bout[n] : 0.f;
}

__global__ void bias_combo(const float* __restrict__ bvec, const float* __restrict__ W,
                           int ldw, const float* __restrict__ badd,
                           float* __restrict__ out, int N)
{
    int n = blockIdx.x*256 + threadIdx.x;
    if (n >= N) return;
    float acc = badd[n];
    for (int k = 0; k < 512; ++k) acc += bvec[k]*W[(size_t)k*ldw + n];
    out[n] = acc;
}

__global__ void init_state(const float* __restrict__ ss,
                           const int* __restrict__ ilo, const int* __restrict__ iro,
                           float* __restrict__ act_f, unsigned short* __restrict__ act_bf,
                           float* __restrict__ aA0, float* __restrict__ bA0,
                           float* __restrict__ aO0, float* __restrict__ bO0)
{
    int i = blockIdx.x*256 + threadIdx.x;
    if (i < BB*DM){
        int d = i >> 6, b = i & 63;
        float v = ss[d];
        act_f[(size_t)b*DM + d] = v;
        act_bf[(size_t)b*DM + d] = f2bfu(v);
    }
    if (i < BB*NS){
        int j = i & (NS-1);
        aA0[i] = 0.f; bA0[i] = 0.f;
        aO0[i] = ss[ilo[j]]*ss[iro[j]];
        bO0[i] = 1.f;
    }
}

// ---------------- cooperative mega-kernel ----------------
struct CTMParams {
    const unsigned short *Kb, *Vb, *WcT, *Wc1T, *WoutT;
    unsigned short *syA, *att, *act_bf, *predA;
    float *act_f, *hpart, *trace;
    const float *bc1, *bc2, *boutp, *lng, *lnb;
    const float *stt, *nw1, *nb1, *nw2, *nb2;
    float *aA, *bA, *aO, *bO;
    const int *ila, *ira, *ilo, *iro;
    const float *dca, *dco;
    float *out_syo;
};

__device__ inline void syncA_step(const CTMParams& P, int b, int rdn, int j){
    float pl = P.act_f[(size_t)b*DM + P.ila[j]];
    float pr = P.act_f[(size_t)b*DM + P.ira[j]];
    float rr = __expf(-fminf(fmaxf(P.dca[j], 0.f), 15.f));
    size_t o = (size_t)b*NS + j;
    float a  = rr*P.aA[(size_t)rdn*SB2 + o] + pl*pr;
    float be = rr*P.bA[(size_t)rdn*SB2 + o] + 1.f;
    P.aA[(size_t)(1-rdn)*SB2 + o] = a;
    P.bA[(size_t)(1-rdn)*SB2 + o] = be;
    P.syA[o] = f2bfu(a*rsqrtf(be));
}

__global__ __launch_bounds__(512, 2) void ctm_loop(CTMParams P)
{
    namespace cg = cooperative_groups;
    cg::grid_group grid = cg::this_grid();
    __shared__ __align__(16) char smem[20480];
    const int bid = blockIdx.x;
    const int tid = threadIdx.x;
    const int lane = tid & 63;
    const int w = tid >> 6;
    const int rf = w & 3;           // MFMA row-fragment
    const int cf2 = (w >> 2) * 2;   // MFMA col-fragment pair base
    const int colb = lane & 15;
    const int koff = (lane >> 4) * 8;
    const int rg4 = (lane >> 4) * 4;

    // prologue: syncA for tick 0
    if (bid >= 64 && bid < 128) syncA_step(P, bid - 64, 0, tid);
    grid.sync();

    for (int t = 0; t < TT; ++t){
        // ---------- P1: Qh tile (MFMA, LDS-resident) + attention ----------
        if (bid < 32){
            int h = bid >> 2, q4 = bid & 3;
            float* qh  = (float*)smem;            // [64][64]
            float* wgt = (float*)(smem + 16384);  // [16][64]
            f32x4_t acc0 = {0.f,0.f,0.f,0.f}, acc1 = {0.f,0.f,0.f,0.f};
            int arow = rf*16 + colb;
            int brow0 = h*64 + cf2*16 + colb;
            int brow1 = brow0 + 16;
            #pragma unroll
            for (int ks = 0; ks < 8; ++ks){
                int k0 = ks*64;
                bf16x8_t a0 = *(const bf16x8_t*)&P.syA[(size_t)arow*NS + k0 + koff];
                bf16x8_t a1 = *(const bf16x8_t*)&P.syA[(size_t)arow*NS + k0 + 32 + koff];
                bf16x8_t b00 = *(const bf16x8_t*)&P.Wc1T[(size_t)brow0*NS + k0 + koff];
                bf16x8_t b01 = *(const bf16x8_t*)&P.Wc1T[(size_t)brow0*NS + k0 + 32 + koff];
                bf16x8_t b10 = *(const bf16x8_t*)&P.Wc1T[(size_t)brow1*NS + k0 + koff];
                bf16x8_t b11 = *(const bf16x8_t*)&P.Wc1T[(size_t)brow1*NS + k0 + 32 + koff];
                acc0 = __builtin_amdgcn_mfma_f32_16x16x32_bf16(a0, b00, acc0, 0, 0, 0);
                acc0 = __builtin_amdgcn_mfma_f32_16x16x32_bf16(a1, b01, acc0, 0, 0, 0);
                acc1 = __builtin_amdgcn_mfma_f32_16x16x32_bf16(a0, b10, acc1, 0, 0, 0);
                acc1 = __builtin_amdgcn_mfma_f32_16x16x32_bf16(a1, b11, acc1, 0, 0, 0);
            }
            #pragma unroll
            for (int r = 0; r < 4; ++r){
                int row = rf*16 + rg4 + r;
                int c0 = cf2*16 + colb, c1 = c0 + 16;
                qh[row*64 + c0] = acc0[r] + P.bc1[h*64 + c0];
                qh[row*64 + c1] = acc1[r] + P.bc1[h*64 + c1];
            }
            __syncthreads();
            // scores + softmax: wave w handles 2 batches
            #pragma unroll
            for (int rep = 0; rep < 2; ++rep){
                int bl = w*2 + rep;
                int b = q4*16 + bl;
                const unsigned short* kp = P.Kb + ((size_t)(b*SS + lane))*DA + (size_t)h*HD;
                float sc = 0.f;
                #pragma unroll
                for (int dg = 0; dg < 8; ++dg){
                    u16x8_t kv = *(const u16x8_t*)(kp + dg*8);
                    #pragma unroll
                    for (int u = 0; u < 8; ++u) sc += qh[b*64 + dg*8 + u]*bfs2f(kv[u]);
                }
                sc *= 0.125f;
                float m = sc;
                for (int o = 32; o; o >>= 1) m = fmaxf(m, __shfl_xor(m, o, 64));
                float e = __expf(sc - m);
                float sum = e;
                for (int o = 32; o; o >>= 1) sum += __shfl_xor(sum, o, 64);
                wgt[bl*64 + lane] = e/sum;
            }
            __syncthreads();
            // PV: 1024 (bl,d) units over 512 threads
            #pragma unroll
            for (int rep = 0; rep < 2; ++rep){
                int idx = rep*512 + tid;
                int bl = idx >> 6, d = idx & 63;
                int b = q4*16 + bl;
                const unsigned short* vp = P.Vb + ((size_t)(b*SS))*DA + (size_t)h*HD + d;
                float o = 0.f;
                #pragma unroll 8
                for (int s = 0; s < SS; ++s) o += wgt[bl*64 + s]*bfs2f(vp[(size_t)s*DA]);
                P.att[(size_t)b*DA + h*HD + d] = f2bfu(o);
            }
        }
        grid.sync();

        // ---------- P2: hgemm  h = [att|act] @ WcT^T  (256 blocks: cg x kc) ----------
        {
            int cgx = bid >> 2, kc = bid & 3;
            int n0 = cgx*64;
            unsigned short* Al = (unsigned short*)smem;            // [64][72]
            unsigned short* Bl = (unsigned short*)(smem + 9216);   // [64][72]
            f32x4_t acc0 = {0.f,0.f,0.f,0.f}, acc1 = {0.f,0.f,0.f,0.f};
            for (int step = 0; step < 10; ++step){
                int k0 = kc*KCH + step*64;
                if (tid < 512){
                    if (tid < 512){
                        int i = tid;
                        int row = i >> 3, kg = (i & 7)*8;
                        // first 512 ids: B; recompute for A below
                        *(uint4*)&Bl[row*72 + kg] =
                            *(const uint4*)&P.WcT[(size_t)(n0+row)*KTOT + k0 + kg];
                        uint4 av;
                        if (k0 < 512) av = *(const uint4*)&P.att[(size_t)row*DA + k0 + kg];
                        else          av = *(const uint4*)&P.act_bf[(size_t)row*DM + (k0-512) + kg];
                        *(uint4*)&Al[row*72 + kg] = av;
                    }
                }
                __syncthreads();
                int arow = rf*16 + colb;
                bf16x8_t a0 = *(const bf16x8_t*)&Al[arow*72 + koff];
                bf16x8_t a1 = *(const bf16x8_t*)&Al[arow*72 + 32 + koff];
                int br0 = cf2*16 + colb, br1 = br0 + 16;
                bf16x8_t b00 = *(const bf16x8_t*)&Bl[br0*72 + koff];
                bf16x8_t b01 = *(const bf16x8_t*)&Bl[br0*72 + 32 + koff];
                bf16x8_t b10 = *(const bf16x8_t*)&Bl[br1*72 + koff];
                bf16x8_t b11 = *(const bf16x8_t*)&Bl[br1*72 + 32 + koff];
                acc0 = __builtin_amdgcn_mfma_f32_16x16x32_bf16(a0, b00, acc0, 0, 0, 0);
                acc0 = __builtin_amdgcn_mfma_f32_16x16x32_bf16(a1, b01, acc0, 0, 0, 0);
                acc1 = __builtin_amdgcn_mfma_f32_16x16x32_bf16(a0, b10, acc1, 0, 0, 0);
                acc1 = __builtin_amdgcn_mfma_f32_16x16x32_bf16(a1, b11, acc1, 0, 0, 0);
                __syncthreads();
            }
            float* out = P.hpart + (size_t)kc*BB*2*DM;
            #pragma unroll
            for (int r = 0; r < 4; ++r){
                int row = rf*16 + rg4 + r;
                out[(size_t)row*2*DM + n0 + cf2*16 + colb]     = acc0[r];
                out[(size_t)row*2*DM + n0 + (cf2+1)*16 + colb] = acc1[r];
            }
        }
        grid.sync();

        // ---------- P3: GLU + LayerNorm -> trace slot ----------
        if (bid < 64){
            int b = bid;
            float* red = (float*)smem;
            float sv[4];
            float lsum = 0.f, lsq = 0.f;
            #pragma unroll
            for (int i = 0; i < 4; ++i){
                int n = tid + i*512;
                float h1 = P.bc2[n], h2 = P.bc2[DM + n];
                #pragma unroll
                for (int c = 0; c < 4; ++c){
                    const float* hp = P.hpart + (size_t)c*BB*2*DM + (size_t)b*2*DM;
                    h1 += hp[n]; h2 += hp[DM + n];
                }
                float s = h1 * (1.f/(1.f + __expf(-h2)));
                sv[i] = s; lsum += s; lsq += s*s;
            }
            for (int o = 32; o; o >>= 1){ lsum += __shfl_down(lsum, o, 64); lsq += __shfl_down(lsq, o, 64); }
            if (lane == 0){ red[w] = lsum; red[8 + w] = lsq; }
            __syncthreads();
            float tsum = 0.f, tsq = 0.f;
            #pragma unroll
            for (int k = 0; k < 8; ++k){ tsum += red[k]; tsq += red[8+k]; }
            float mu = tsum/DM;
            float var = tsq/DM - mu*mu;
            float inv = rsqrtf(var + 1e-5f);
            int slot = t % MM;
            float* tr = P.trace + (size_t)slot*DM*BB;
            #pragma unroll
            for (int i = 0; i < 4; ++i){
                int n = tid + i*512;
                tr[(size_t)n*BB + b] = (sv[i] - mu)*inv*P.lng[n] + P.lnb[n];
            }
        }
        grid.sync();

        // ---------- P4: neuron-level models (8 d per block) ----------
        {
            float* w1  = (float*)smem;           // [25][32]
            float* tr  = (float*)(smem + 3200);  // [25][64]
            float* w2v = (float*)(smem + 9600);  // [32]
            float* b1v = (float*)(smem + 9728);  // [32]
            float* red = (float*)(smem + 9856);  // [8][64]
            for (int dd = 0; dd < 8; ++dd){
                int d = bid*8 + dd;
                for (int i = tid; i < MM*HN; i += 512) w1[i] = P.nw1[(size_t)d*MM*HN + i];
                if (tid < HN){ w2v[tid] = P.nw2[d*HN + tid]; b1v[tid] = P.nb1[d*HN + tid]; }
                for (int i = tid; i < MM*BB; i += 512){
                    int m = i >> 6, b = i & 63;
                    int time = t - (MM-1) + m;
                    tr[i] = (time >= 0) ? P.trace[(size_t)(time % MM)*DM*BB + (size_t)d*BB + b]
                                        : P.stt[(size_t)d*MM + (m + t + 1)];
                }
                __syncthreads();
                int b = tid & 63, hg = tid >> 6;
                float pa = 0.f;
                #pragma unroll
                for (int hh = 0; hh < 4; ++hh){
                    int h = hg*4 + hh;
                    float a = b1v[h];
                    #pragma unroll
                    for (int m = 0; m < MM; ++m) a += tr[m*64 + b]*w1[m*32 + h];
                    pa += gelu_tanh(a)*w2v[h];
                }
                red[hg*64 + b] = pa;
                __syncthreads();
                if (tid < 64){
                    float v = P.nb2[d];
                    #pragma unroll
                    for (int k = 0; k < 8; ++k) v += red[k*64 + tid];
                    P.act_f[(size_t)tid*DM + d] = v;
                    P.act_bf[(size_t)tid*DM + d] = f2bfu(v);
                }
                __syncthreads();
            }
        }
        grid.sync();

        // ---------- P6: pred (MFMA, redundant syncO) + syncA(t+1) ----------
        if (bid < 16){
            unsigned short* Asy = (unsigned short*)smem;   // [64][72]
            int n0 = bid*64;
            int rd = t & 1, wr2 = 1 - rd;
            f32x4_t acc0 = {0.f,0.f,0.f,0.f}, acc1 = {0.f,0.f,0.f,0.f};
            for (int ks = 0; ks < 8; ++ks){
                int jj = tid & 63, bq = tid >> 6;
                int j = ks*64 + jj;
                int ilj = P.ilo[j], irj = P.iro[j];
                float rr = __expf(-fminf(fmaxf(P.dco[j], 0.f), 15.f));
                #pragma unroll
                for (int p = 0; p < 8; ++p){
                    int b = p*8 + bq;
                    float pair = P.act_f[(size_t)b*DM + ilj]*P.act_f[(size_t)b*DM + irj];
                    size_t o = (size_t)b*NS + j;
                    float a  = rr*P.aO[(size_t)rd*SB2 + o] + pair;
                    float be = rr*P.bO[(size_t)rd*SB2 + o] + 1.f;
                    float s = a*rsqrtf(be);
                    Asy[b*72 + jj] = f2bfu(s);
                    if (bid == 0){
                        P.aO[(size_t)wr2*SB2 + o] = a;
                        P.bO[(size_t)wr2*SB2 + o] = be;
                        if (t == TT-1) P.out_syo[o] = s;
                    }
                }
                __syncthreads();
                int arow = rf*16 + colb;
                bf16x8_t a0 = *(const bf16x8_t*)&Asy[arow*72 + koff];
                bf16x8_t a1 = *(const bf16x8_t*)&Asy[arow*72 + 32 + koff];
                int br0 = n0 + cf2*16 + colb, br1 = br0 + 16;
                bf16x8_t b00 = *(const bf16x8_t*)&P.WoutT[(size_t)br0*NS + ks*64 + koff];
                bf16x8_t b01 = *(const bf16x8_t*)&P.WoutT[(size_t)br0*NS + ks*64 + 32 + koff];
                bf16x8_t b10 = *(const bf16x8_t*)&P.WoutT[(size_t)br1*NS + ks*64 + koff];
                bf16x8_t b11 = *(const bf16x8_t*)&P.WoutT[(size_t)br1*NS + ks*64 + 32 + koff];
                acc0 = __builtin_amdgcn_mfma_f32_16x16x32_bf16(a0, b00, acc0, 0, 0, 0);
                acc0 = __builtin_amdgcn_mfma_f32_16x16x32_bf16(a1, b01, acc0, 0, 0, 0);
                acc1 = __builtin_amdgcn_mfma_f32_16x16x32_bf16(a0, b10, acc1, 0, 0, 0);
                acc1 = __builtin_amdgcn_mfma_f32_16x16x32_bf16(a1, b11, acc1, 0, 0, 0);
                __syncthreads();
            }
            unsigned short* pa = P.predA + (size_t)t*BB*NPAD;
            #pragma unroll
            for (int r = 0; r < 4; ++r){
                int row = rf*16 + rg4 + r;
                int c0 = n0 + cf2*16 + colb, c1 = c0 + 16;
                pa[(size_t)row*NPAD + c0] = f2bfu(acc0[r] + P.boutp[c0]);
                pa[(size_t)row*NPAD + c1] = f2bfu(acc1[r] + P.boutp[c1]);
            }
        } else if (bid >= 64 && bid < 128){
            syncA_step(P, bid - 64, (t+1) & 1, tid);
        }
        grid.sync();
    }
}

// ---------------- post-loop kernels ----------------
__global__ void entropy_k(const unsigned short* __restrict__ predA, float* __restrict__ out_cert)
{
    __shared__ float red[8];
    int b = blockIdx.x & 63, t = blockIdx.x >> 6, tid = threadIdx.x;
    const unsigned short* pr = predA + (size_t)t*BB*NPAD + (size_t)b*NPAD;
    float v[4];
    float m = -1e30f;
    #pragma unroll
    for (int i = 0; i < 4; ++i){
        int n = tid + i*256;
        v[i] = (n < NOUT) ? bfs2f(pr[n]) : -1e30f;
        m = fmaxf(m, v[i]);
    }
    for (int o = 32; o; o >>= 1) m = fmaxf(m, __shfl_xor(m, o, 64));
    if ((tid & 63) == 0) red[tid >> 6] = m;
    __syncthreads();
    m = fmaxf(fmaxf(red[0], red[1]), fmaxf(red[2], red[3]));
    __syncthreads();
    float s1 = 0.f, s2 = 0.f;
    #pragma unroll
    for (int i = 0; i < 4; ++i){
        int n = tid + i*256;
        if (n < NOUT){
            float e = __expf(v[i] - m);
            s1 += e; s2 += e*(v[i] - m);
        }
    }
    for (int o = 32; o; o >>= 1){ s1 += __shfl_xor(s1, o, 64); s2 += __shfl_xor(s2, o, 64); }
    if ((tid & 63) == 0){ red[tid >> 6] = s1; red[4 + (tid >> 6)] = s2; }
    __syncthreads();
    s1 = red[0]+red[1]+red[2]+red[3];
    s2 = red[4]+red[5]+red[6]+red[7];
    float plogp = s2/s1 - logf(s1);
    float ne = -plogp / logf((float)NOUT);
    if (tid == 0){
        out_cert[(size_t)b*2*TT + t]      = ne;
        out_cert[(size_t)b*2*TT + TT + t] = 1.f - ne;
    }
}

// pred_all[t][b][n] -> out_pred[b][n][t]  (coalesced both sides)
__global__ void transpose_pred(const unsigned short* __restrict__ predA, float* __restrict__ out_pred)
{
    __shared__ unsigned short sm[50][136];
    int bx = blockIdx.x;   // n-tile (8 x 128)
    int b  = blockIdx.y;
    int tid = threadIdx.x;
    for (int tp = 0; tp < 25; ++tp){
        int t = tp*2 + (tid >> 7);
        int nn = tid & 127;
        sm[t][nn] = predA[(size_t)t*BB*NPAD + (size_t)b*NPAD + bx*128 + nn];
    }
    __syncthreads();
    int nloc = tid >> 1, half = tid & 1;
    int n = bx*128 + nloc;
    if (n < NOUT){
        float* dst = out_pred + (size_t)b*NOUT*TT + (size_t)n*TT + half*25;
        #pragma unroll
        for (int q = 0; q < 25; ++q) dst[q] = bfs2f(sm[half*25 + q][nloc]);
    }
}

extern "C" void kernel_launch(void* const* d_in, const int* in_sizes, int n_in,
                              void* d_out, int out_size, void* d_ws, size_t ws_size,
                              hipStream_t stream)
{
    const float* x    = (const float*)d_in[0];
    const float* Wf   = (const float*)d_in[1];
    const float* bf   = (const float*)d_in[2];
    const float* stt  = (const float*)d_in[3];
    const float* ss   = (const float*)d_in[4];
    const float* dca  = (const float*)d_in[5];
    const float* dco  = (const float*)d_in[6];
    const float* Wqp  = (const float*)d_in[7];
    const float* bqp  = (const float*)d_in[8];
    const float* Wq   = (const float*)d_in[9];
    const float* bq   = (const float*)d_in[10];
    const float* Wk   = (const float*)d_in[11];
    const float* bk   = (const float*)d_in[12];
    const float* Wv   = (const float*)d_in[13];
    const float* bv   = (const float*)d_in[14];
    const float* Wo   = (const float*)d_in[15];
    const float* bo   = (const float*)d_in[16];
    const float* Ws1  = (const float*)d_in[17];
    const float* bs1  = (const float*)d_in[18];
    const float* lng  = (const float*)d_in[19];
    const float* lnb  = (const float*)d_in[20];
    const float* nw1  = (const float*)d_in[21];
    const float* nb1  = (const float*)d_in[22];
    const float* nw2  = (const float*)d_in[23];
    const float* nb2  = (const float*)d_in[24];
    const float* Wout = (const float*)d_in[25];
    const float* bout = (const float*)d_in[26];
    const int* ila = (const int*)d_in[27];
    const int* ira = (const int*)d_in[28];
    const int* ilo = (const int*)d_in[29];
    const int* iro = (const int*)d_in[30];

    float* ws = (float*)d_ws;
    unsigned short* Kb    = (unsigned short*)(ws + OFF_K);
    unsigned short* Vb    = (unsigned short*)(ws + OFF_V);
    unsigned short* WcT   = (unsigned short*)(ws + OFF_WCT);
    unsigned short* Wc1T  = (unsigned short*)(ws + OFF_WC1T);
    unsigned short* WoutT = (unsigned short*)(ws + OFF_WOUTT);
    float* Wfk   = ws + OFF_WFK;
    float* Wfv   = ws + OFF_WFV;
    float* bfk   = ws + OFF_BFK;
    float* bfv   = ws + OFF_BFV;
    float* bc1   = ws + OFF_BC1;
    float* bc2   = ws + OFF_BC2;
    float* boutp = ws + OFF_BOUTP;
    float* aA    = ws + OFF_AA;
    float* bA    = ws + OFF_BA;
    float* aO    = ws + OFF_AO;
    float* bO    = ws + OFF_BO;
    unsigned short* syA   = (unsigned short*)(ws + OFF_SYA);
    unsigned short* attb  = (unsigned short*)(ws + OFF_ATTB);
    unsigned short* actb  = (unsigned short*)(ws + OFF_ACTB);
    float* actf  = ws + OFF_ACTF;
    float* hpart = ws + OFF_HPART;
    float* trace = ws + OFF_TRACE;
    unsigned short* predA = (unsigned short*)(ws + OFF_PREDA);

    float* outp = (float*)d_out;
    float* out_pred = outp;
    float* out_cert = outp + (size_t)BB*NOUT*TT;
    float* out_syo  = out_cert + (size_t)BB*2*TT;

    // ---- setup ----
    sgemm64<<<dim3(8,8),  256, 0, stream>>>(Wf, 512, Wk, 512, nullptr, Wfk, 512, 512);
    sgemm64<<<dim3(8,8),  256, 0, stream>>>(Wf, 512, Wv, 512, nullptr, Wfv, 512, 512);
    gemm_t_bf16<<<dim3(8,8),  256, 0, stream>>>(Wqp, Wq, 512,  Wc1T, 512);
    gemm_t_bf16<<<dim3(64,8), 256, 0, stream>>>(Wo,  Ws1, 4096, WcT, KTOT);
    tcvt_ws1<<<dim3(128,64), 256, 0, stream>>>(Ws1, WcT);
    tcvt_wout<<<NPAD, 256, 0, stream>>>(Wout, bout, WoutT, boutp);
    bias_combo<<<2, 256, 0, stream>>>(bf,  Wk, 512, bk, bfk, 512);
    bias_combo<<<2, 256, 0, stream>>>(bf,  Wv, 512, bv, bfv, 512);
    bias_combo<<<2, 256, 0, stream>>>(bqp, Wq, 512, bq, bc1, 512);
    bias_combo<<<16,256, 0, stream>>>(bo,  Ws1,4096, bs1, bc2, 4096);
    sgemm64_bf16out<<<dim3(8,64), 256, 0, stream>>>(x, 512, Wfk, 512, bfk, (__hip_bfloat16*)Kb, 512, 512);
    sgemm64_bf16out<<<dim3(8,64), 256, 0, stream>>>(x, 512, Wfv, 512, bfv, (__hip_bfloat16*)Vb, 512, 512);
    init_state<<<512, 256, 0, stream>>>(ss, ilo, iro, actf, actb, aA, bA, aO, bO);

    // ---- cooperative tick loop ----
    CTMParams prm;
    prm.Kb = Kb; prm.Vb = Vb; prm.WcT = WcT; prm.Wc1T = Wc1T; prm.WoutT = WoutT;
    prm.syA = syA; prm.att = attb; prm.act_bf = actb; prm.predA = predA;
    prm.act_f = actf; prm.hpart = hpart; prm.trace = trace;
    prm.bc1 = bc1; prm.bc2 = bc2; prm.boutp = boutp; prm.lng = lng; prm.lnb = lnb;
    prm.stt = stt; prm.nw1 = nw1; prm.nb1 = nb1; prm.nw2 = nw2; prm.nb2 = nb2;
    prm.aA = aA; prm.bA = bA; prm.aO = aO; prm.bO = bO;
    prm.ila = ila; prm.ira = ira; prm.ilo = ilo; prm.iro = iro;
    prm.dca = dca; prm.dco = dco;
    prm.out_syo = out_syo;
    void* args[] = { &prm };
    hipLaunchCooperativeKernel((const void*)ctm_loop, dim3(256), dim3(512), args, 0, stream);

    // ---- outputs ----
    entropy_k<<<TT*BB, 256, 0, stream>>>(predA, out_cert);
    transpose_pred<<<dim3(8, BB), 256, 0, stream>>>(predA, out_pred);
}